// Round 1
// baseline (433.461 us; speedup 1.0000x reference)
//
#include <hip/hip_runtime.h>
#include <hip/hip_bf16.h>
#include <type_traits>

#define DEV __device__ __forceinline__

typedef __bf16 bf16x8 __attribute__((ext_vector_type(8)));
typedef float f32x4 __attribute__((ext_vector_type(4)));
typedef unsigned short u16;
typedef unsigned int u32;

// ---------- helpers ----------
DEV u16 f32_to_bf16(float f) {                 // round-to-nearest-even
  union { float f; u32 u; } x; x.f = f;
  u32 r = (x.u + 0x7FFFu + ((x.u >> 16) & 1u)) >> 16;
  return (u16)r;
}

// async global->LDS, 16B per lane. HW writes wave-uniform base + lane*16 (linear).
DEV void ld_lds16(const void* g, void* l) {
  __builtin_amdgcn_global_load_lds(
      (const __attribute__((address_space(1))) u32*)g,
      (__attribute__((address_space(3))) u32*)l, 16, 0, 0);
}

#define MFMA16(a, b, c) __builtin_amdgcn_mfma_f32_16x16x32_bf16(a, b, c, 0, 0, 0)

// ---------- cast f32 -> bf16 (vectorized, memory-bound) ----------
__global__ __launch_bounds__(256) void cast_kernel(const float* __restrict__ in,
                                                   u16* __restrict__ out, int n) {
  int i = (blockIdx.x * 256 + threadIdx.x) * 4;
  if (i >= n) return;
  float4 v = *reinterpret_cast<const float4*>(in + i);
  ushort4 o;
  o.x = f32_to_bf16(v.x); o.y = f32_to_bf16(v.y);
  o.z = f32_to_bf16(v.z); o.w = f32_to_bf16(v.w);
  *reinterpret_cast<ushort4*>(out + i) = o;
}

// ---------- GEMM: C[M][N] = A[M][K] * B[N][K]^T  (bf16 in, f32 acc) ----------
// 128x128 tile, BK=64, 4 waves (2x2), 16x16x32 MFMA.
// LDS linear (global_load_lds) + XOR source-swizzle; reads apply same XOR
// -> ~2-way instead of 16-way bank conflicts on ds_read_b128.
template <typename OutT>
__global__ __launch_bounds__(256) void gemm_nt(const u16* __restrict__ A,
                                               const u16* __restrict__ B,
                                               OutT* __restrict__ C,
                                               int M, int N, int K) {
  __shared__ __align__(16) u16 sA[128 * 64];
  __shared__ __align__(16) u16 sB[128 * 64];
  const int tid = threadIdx.x;
  const int lane = tid & 63, wid = tid >> 6;
  const int lo = lane & 15, hi = lane >> 4;
  const int wm = wid >> 1, wn = wid & 1;
  const int m0 = blockIdx.y * 128, n0 = blockIdx.x * 128;

  f32x4 acc[4][4] = {};

  for (int k0 = 0; k0 < K; k0 += 64) {
    __syncthreads();
#pragma unroll
    for (int i = 0; i < 4; ++i) {
      int e16 = i * 256 + tid;                      // 16B chunk, 0..1023
      int r = e16 >> 3;                             // 8 chunks (128B) per row
      int bcol = ((e16 & 7) * 16) ^ ((r & 7) << 4); // inverse-swizzled source col
      int col = bcol >> 1;
      ld_lds16(A + (size_t)(m0 + r) * K + k0 + col, sA + e16 * 8);
      ld_lds16(B + (size_t)(n0 + r) * K + k0 + col, sB + e16 * 8);
    }
    __syncthreads();
#pragma unroll
    for (int kc = 0; kc < 2; ++kc) {
      bf16x8 a[4], b[4];
#pragma unroll
      for (int i = 0; i < 4; ++i) {
        int row = wm * 64 + i * 16 + lo;
        int boff = ((kc * 32 + hi * 8) * 2) ^ ((row & 7) << 4);
        a[i] = *(const bf16x8*)((const char*)sA + row * 128 + boff);
      }
#pragma unroll
      for (int i = 0; i < 4; ++i) {
        int row = wn * 64 + i * 16 + lo;
        int boff = ((kc * 32 + hi * 8) * 2) ^ ((row & 7) << 4);
        b[i] = *(const bf16x8*)((const char*)sB + row * 128 + boff);
      }
#pragma unroll
      for (int mi = 0; mi < 4; ++mi)
#pragma unroll
        for (int ni = 0; ni < 4; ++ni)
          acc[mi][ni] = MFMA16(a[mi], b[ni], acc[mi][ni]);
    }
  }
  // epilogue: C/D layout col=lane&15, row=(lane>>4)*4+reg
#pragma unroll
  for (int mi = 0; mi < 4; ++mi)
#pragma unroll
    for (int r = 0; r < 4; ++r) {
      size_t row = m0 + wm * 64 + mi * 16 + hi * 4 + r;
#pragma unroll
      for (int ni = 0; ni < 4; ++ni) {
        int col = n0 + wn * 64 + ni * 16 + lo;
        float v = acc[mi][ni][r];
        if constexpr (std::is_same<OutT, float>::value)
          C[row * N + col] = v;
        else
          C[row * N + col] = f32_to_bf16(v);
      }
    }
}

// ---------- causal flash attention ----------
// [B,S,H,Dh] layout (row stride 2048). QT=64 rows/block (4 waves x 16),
// KVT=64. K staged swizzled via global_load_lds; V staged transposed
// (padded rows of 72 elems = 144B, 16B aligned, ~2-way conflicts);
// P round-trips per-wave LDS to convert C-layout -> A-fragment layout.
constexpr int ATT_S = 2048, ATT_D = 2048, ATT_DH = 128;
constexpr float SM_SCALE = 0.08838834764831845f;  // 1/sqrt(128)

__global__ __launch_bounds__(256) void attn_fwd(const u16* __restrict__ Q,
                                                const u16* __restrict__ K,
                                                const u16* __restrict__ V,
                                                u16* __restrict__ O) {
  __shared__ __align__(16) u16 sK[64 * 128];   // swizzled content, linear
  __shared__ __align__(16) u16 sVT[128 * 72];  // transposed V, padded
  __shared__ __align__(16) u16 sP[4][16 * 72]; // per-wave P buffer

  const int qt = (ATT_S / 64 - 1) - blockIdx.x;  // heavy tiles first
  const int h = blockIdx.y, b = blockIdx.z;
  const int tid = threadIdx.x;
  const int lane = tid & 63, wid = tid >> 6;
  const int lo = lane & 15, hi = lane >> 4;

  const size_t base = ((size_t)b * ATT_S) * ATT_D + (size_t)h * ATT_DH;
  const int q0 = qt * 64;
  const int qrow = q0 + wid * 16;

  // Q fragments live in registers for the whole block
  bf16x8 qf[4];
#pragma unroll
  for (int c = 0; c < 4; ++c)
    qf[c] = *(const bf16x8*)(Q + base + (size_t)(qrow + lo) * ATT_D + c * 32 + hi * 8);

  f32x4 o[8] = {};
  float m[4], ls[4];
#pragma unroll
  for (int r = 0; r < 4; ++r) { m[r] = -INFINITY; ls[r] = 0.f; }

  for (int t = 0; t <= qt; ++t) {
    const int kv0 = t * 64;
    __syncthreads();
    // stage K (swizzled source -> linear LDS)
#pragma unroll
    for (int i = 0; i < 4; ++i) {
      int e16 = i * 256 + tid;                       // 16 chunks per 256B row
      int r = e16 >> 4;
      int bcol = ((e16 & 15) * 16) ^ ((r & 7) << 4);
      ld_lds16(K + base + (size_t)(kv0 + r) * ATT_D + (bcol >> 1), sK + e16 * 8);
    }
    // stage V transposed: key = lane (conflict-free writes), dh rows per wave
#pragma unroll
    for (int i = 0; i < 4; ++i) {
      int dh0 = wid * 32 + i * 8;
      bf16x8 vv = *(const bf16x8*)(V + base + (size_t)(kv0 + lane) * ATT_D + dh0);
      const u16* pv = (const u16*)&vv;
#pragma unroll
      for (int j = 0; j < 8; ++j) sVT[(dh0 + j) * 72 + lane] = pv[j];
    }
    __syncthreads();

    // QK^T: scores s[n] = 16q x 16k fragments, n over 64 keys
    f32x4 s[4];
#pragma unroll
    for (int n = 0; n < 4; ++n) {
      f32x4 a = {};
#pragma unroll
      for (int c = 0; c < 4; ++c) {
        int row = n * 16 + lo;
        int boff = ((c * 32 + hi * 8) * 2) ^ ((row & 7) << 4);
        bf16x8 kf = *(const bf16x8*)((const char*)sK + row * 256 + boff);
        a = MFMA16(qf[c], kf, a);
      }
      s[n] = a;
    }

    const bool diag = (kv0 == q0);  // only diagonal tile needs masking
    float mt[4] = {-3e38f, -3e38f, -3e38f, -3e38f};
#pragma unroll
    for (int n = 0; n < 4; ++n)
#pragma unroll
      for (int r = 0; r < 4; ++r) {
        float x = s[n][r] * SM_SCALE;
        if (diag) {
          int key_g = kv0 + n * 16 + lo;
          int row_g = qrow + hi * 4 + r;
          if (key_g > row_g) x = -3e38f;
        }
        s[n][r] = x;
        mt[r] = fmaxf(mt[r], x);
      }
#pragma unroll
    for (int d = 1; d < 16; d <<= 1)
#pragma unroll
      for (int r = 0; r < 4; ++r) mt[r] = fmaxf(mt[r], __shfl_xor(mt[r], d));

    float f[4], rs[4];
#pragma unroll
    for (int r = 0; r < 4; ++r) {
      float mn = fmaxf(m[r], mt[r]);
      f[r] = __expf(m[r] - mn);   // exp(-inf)=0 on first tile
      m[r] = mn;
      rs[r] = 0.f;
    }
#pragma unroll
    for (int n = 0; n < 4; ++n)
#pragma unroll
      for (int r = 0; r < 4; ++r) {
        float p = __expf(s[n][r] - m[r]);
        s[n][r] = p;
        rs[r] += p;
      }
#pragma unroll
    for (int d = 1; d < 16; d <<= 1)
#pragma unroll
      for (int r = 0; r < 4; ++r) rs[r] += __shfl_xor(rs[r], d);
#pragma unroll
    for (int r = 0; r < 4; ++r) ls[r] = ls[r] * f[r] + rs[r];
#pragma unroll
    for (int d8 = 0; d8 < 8; ++d8)
#pragma unroll
      for (int r = 0; r < 4; ++r) o[d8][r] *= f[r];

    // P: C-layout (row=hi*4+r, col=n*16+lo) -> per-wave LDS -> A-frag layout
    u16* myP = sP[wid];
#pragma unroll
    for (int n = 0; n < 4; ++n)
#pragma unroll
      for (int r = 0; r < 4; ++r)
        myP[(hi * 4 + r) * 72 + n * 16 + lo] = f32_to_bf16(s[n][r]);

    bf16x8 pf[2];
#pragma unroll
    for (int kc = 0; kc < 2; ++kc)
      pf[kc] = *(const bf16x8*)(myP + lo * 72 + kc * 32 + hi * 8);

    // PV: O[q][dh] += P[q][k] * V[k][dh]
#pragma unroll
    for (int kc = 0; kc < 2; ++kc)
#pragma unroll
      for (int d8 = 0; d8 < 8; ++d8) {
        bf16x8 vf = *(const bf16x8*)(sVT + (d8 * 16 + lo) * 72 + kc * 32 + hi * 8);
        o[d8] = MFMA16(pf[kc], vf, o[d8]);
      }
  }

  // normalize + store
  float inv[4];
#pragma unroll
  for (int r = 0; r < 4; ++r) inv[r] = 1.f / ls[r];
#pragma unroll
  for (int r = 0; r < 4; ++r) {
    size_t row = (size_t)b * ATT_S + qrow + hi * 4 + r;
#pragma unroll
    for (int d8 = 0; d8 < 8; ++d8)
      O[row * ATT_D + (size_t)h * ATT_DH + d8 * 16 + lo] = f32_to_bf16(o[d8][r] * inv[r]);
  }
}

// ---------- launch ----------
extern "C" void kernel_launch(void* const* d_in, const int* in_sizes, int n_in,
                              void* d_out, int out_size, void* d_ws, size_t ws_size,
                              hipStream_t stream) {
  const float* x  = (const float*)d_in[0];
  const float* Wq = (const float*)d_in[1];
  const float* Wk = (const float*)d_in[2];
  const float* Wv = (const float*)d_in[3];
  const float* Wo = (const float*)d_in[4];
  float* out = (float*)d_out;

  constexpr int B = 2, S = 2048, D = 2048;
  constexpr int M = B * S;  // 4096

  char* ws = (char*)d_ws;
  u16* xb  = (u16*)ws; ws += (size_t)M * D * 2;
  u16* wqb = (u16*)ws; ws += (size_t)D * D * 2;
  u16* wkb = (u16*)ws; ws += (size_t)D * D * 2;
  u16* wvb = (u16*)ws; ws += (size_t)D * D * 2;
  u16* wob = (u16*)ws; ws += (size_t)D * D * 2;
  u16* q   = (u16*)ws; ws += (size_t)M * D * 2;
  u16* k   = (u16*)ws; ws += (size_t)M * D * 2;
  u16* v   = (u16*)ws; ws += (size_t)M * D * 2;
  u16* att = (u16*)ws; ws += (size_t)M * D * 2;

  cast_kernel<<<M * D / 1024, 256, 0, stream>>>(x, xb, M * D);
  cast_kernel<<<D * D / 1024, 256, 0, stream>>>(Wq, wqb, D * D);
  cast_kernel<<<D * D / 1024, 256, 0, stream>>>(Wk, wkb, D * D);
  cast_kernel<<<D * D / 1024, 256, 0, stream>>>(Wv, wvb, D * D);
  cast_kernel<<<D * D / 1024, 256, 0, stream>>>(Wo, wob, D * D);

  dim3 gg(D / 128, M / 128);
  gemm_nt<u16><<<gg, 256, 0, stream>>>(xb, wqb, q, M, D, D);
  gemm_nt<u16><<<gg, 256, 0, stream>>>(xb, wkb, k, M, D, D);
  gemm_nt<u16><<<gg, 256, 0, stream>>>(xb, wvb, v, M, D, D);

  attn_fwd<<<dim3(S / 64, 16, B), 256, 0, stream>>>(q, k, v, att);

  gemm_nt<float><<<gg, 256, 0, stream>>>(att, wob, out, M, D, D);
}

// Round 2
// 305.749 us; speedup vs baseline: 1.4177x; 1.4177x over previous
//
#include <hip/hip_runtime.h>
#include <hip/hip_bf16.h>
#include <type_traits>

#define DEV __device__ __forceinline__

typedef __bf16 bf16x8 __attribute__((ext_vector_type(8)));
typedef float f32x4 __attribute__((ext_vector_type(4)));
typedef unsigned short u16;
typedef unsigned int u32;

// ---------- helpers ----------
DEV u16 f32_to_bf16(float f) {                 // round-to-nearest-even
  union { float f; u32 u; } x; x.f = f;
  u32 r = (x.u + 0x7FFFu + ((x.u >> 16) & 1u)) >> 16;
  return (u16)r;
}

// async global->LDS, 16B per lane. HW writes wave-uniform base + lane*16 (linear).
DEV void ld_lds16(const void* g, void* l) {
  __builtin_amdgcn_global_load_lds(
      (const __attribute__((address_space(1))) u32*)g,
      (__attribute__((address_space(3))) u32*)l, 16, 0, 0);
}

#define MFMA16(a, b, c) __builtin_amdgcn_mfma_f32_16x16x32_bf16(a, b, c, 0, 0, 0)

// ---------- cast f32 -> bf16 (vectorized, memory-bound) ----------
__global__ __launch_bounds__(256) void cast_kernel(const float* __restrict__ in,
                                                   u16* __restrict__ out, int n) {
  int i = (blockIdx.x * 256 + threadIdx.x) * 4;
  if (i >= n) return;
  float4 v = *reinterpret_cast<const float4*>(in + i);
  ushort4 o;
  o.x = f32_to_bf16(v.x); o.y = f32_to_bf16(v.y);
  o.z = f32_to_bf16(v.z); o.w = f32_to_bf16(v.w);
  *reinterpret_cast<ushort4*>(out + i) = o;
}

// ---------- GEMM: C[M][N] = A[M][K] * B[N][K]^T  (bf16 in, f32 acc) ----------
// 128x128 tile, BK=64, 4 waves (2x2), 16x16x32 MFMA.
// LDS linear (global_load_lds) + XOR source-swizzle; reads apply same XOR.
template <typename OutT>
__global__ __launch_bounds__(256) void gemm_nt(const u16* __restrict__ A,
                                               const u16* __restrict__ B,
                                               OutT* __restrict__ C,
                                               int M, int N, int K) {
  __shared__ __align__(16) u16 sA[128 * 64];
  __shared__ __align__(16) u16 sB[128 * 64];
  const int tid = threadIdx.x;
  const int lane = tid & 63, wid = tid >> 6;
  const int lo = lane & 15, hi = lane >> 4;
  const int wm = wid >> 1, wn = wid & 1;
  const int m0 = blockIdx.y * 128, n0 = blockIdx.x * 128;

  f32x4 acc[4][4] = {};

  for (int k0 = 0; k0 < K; k0 += 64) {
    __syncthreads();
#pragma unroll
    for (int i = 0; i < 4; ++i) {
      int e16 = i * 256 + tid;                      // 16B chunk, 0..1023
      int r = e16 >> 3;                             // 8 chunks (128B) per row
      int bcol = ((e16 & 7) * 16) ^ ((r & 7) << 4); // inverse-swizzled source col
      int col = bcol >> 1;
      ld_lds16(A + (size_t)(m0 + r) * K + k0 + col, sA + e16 * 8);
      ld_lds16(B + (size_t)(n0 + r) * K + k0 + col, sB + e16 * 8);
    }
    __syncthreads();
#pragma unroll
    for (int kc = 0; kc < 2; ++kc) {
      bf16x8 a[4], b[4];
#pragma unroll
      for (int i = 0; i < 4; ++i) {
        int row = wm * 64 + i * 16 + lo;
        int boff = ((kc * 32 + hi * 8) * 2) ^ ((row & 7) << 4);
        a[i] = *(const bf16x8*)((const char*)sA + row * 128 + boff);
      }
#pragma unroll
      for (int i = 0; i < 4; ++i) {
        int row = wn * 64 + i * 16 + lo;
        int boff = ((kc * 32 + hi * 8) * 2) ^ ((row & 7) << 4);
        b[i] = *(const bf16x8*)((const char*)sB + row * 128 + boff);
      }
#pragma unroll
      for (int mi = 0; mi < 4; ++mi)
#pragma unroll
        for (int ni = 0; ni < 4; ++ni)
          acc[mi][ni] = MFMA16(a[mi], b[ni], acc[mi][ni]);
    }
  }
#pragma unroll
  for (int mi = 0; mi < 4; ++mi)
#pragma unroll
    for (int r = 0; r < 4; ++r) {
      size_t row = m0 + wm * 64 + mi * 16 + hi * 4 + r;
#pragma unroll
      for (int ni = 0; ni < 4; ++ni) {
        int col = n0 + wn * 64 + ni * 16 + lo;
        float v = acc[mi][ni][r];
        if constexpr (std::is_same<OutT, float>::value)
          C[row * N + col] = v;
        else
          C[row * N + col] = f32_to_bf16(v);
      }
    }
}

// ---------- causal flash attention ----------
// Q,K: [tok=4096][feat=2048]; VT: [feat=2048][tok=4096] (V pre-transposed by
// its GEMM). 128 q-rows/block (4 waves x 2 frags of 16), KV tile 64.
// K and VT staged via swizzled global_load_lds, double-buffered; per-wave
// P round-trip through LDS converts C-layout -> A-frag layout.
constexpr float SM_SCALE = 0.08838834764831845f;  // 1/sqrt(128)

__global__ __launch_bounds__(256, 2) void attn_fwd(const u16* __restrict__ Q,
                                                   const u16* __restrict__ K,
                                                   const u16* __restrict__ VT,
                                                   u16* __restrict__ O) {
  __shared__ __align__(16) u16 sK[2][64 * 128];   // [kv 64][dh 128], swizzled
  __shared__ __align__(16) u16 sV[2][128 * 64];   // [dh 128][kv 64], swizzled
  __shared__ __align__(16) u16 sP[4][16 * 72];    // per-wave P buffer

  const int x = blockIdx.x, h = blockIdx.y, b = blockIdx.z;
  const int qt = b ? x : (15 - x);   // anti-correlated pairing across z
  const int tid = threadIdx.x;
  const int lane = tid & 63, wid = tid >> 6;
  const int lo = lane & 15, hi = lane >> 4;

  const size_t baseQK = ((size_t)b * 2048) * 2048 + (size_t)h * 128;
  const size_t baseV  = ((size_t)h * 128) * 4096 + (size_t)b * 2048;
  const int q0 = qt * 128;
  const int nt = 2 * qt + 2;

  // Q fragments in registers for the whole block: 2 frags x 4 k-chunks
  bf16x8 qf[2][4];
#pragma unroll
  for (int f = 0; f < 2; ++f)
#pragma unroll
    for (int c = 0; c < 4; ++c)
      qf[f][c] = *(const bf16x8*)(Q + baseQK +
                                  (size_t)(q0 + wid * 32 + f * 16 + lo) * 2048 +
                                  c * 32 + hi * 8);

  f32x4 o2[2][8] = {};
  float m[2][4], ls[2][4];
#pragma unroll
  for (int f = 0; f < 2; ++f)
#pragma unroll
    for (int r = 0; r < 4; ++r) { m[f][r] = -INFINITY; ls[f][r] = 0.f; }

  auto stage = [&](int buf, int t) {
    const int kv = t * 64;
#pragma unroll
    for (int i = 0; i < 4; ++i) {   // K tile: 64 rows x 256B = 1024 chunks
      int e = i * 256 + tid;
      int r = e >> 4;
      int bc = ((e & 15) * 16) ^ ((r & 7) << 4);
      ld_lds16(K + baseQK + (size_t)(kv + r) * 2048 + (bc >> 1), &sK[buf][e * 8]);
    }
#pragma unroll
    for (int i = 0; i < 4; ++i) {   // VT tile: 128 rows x 128B = 1024 chunks
      int e = i * 256 + tid;
      int r = e >> 3;
      int bc = ((e & 7) * 16) ^ ((r & 7) << 4);
      ld_lds16(VT + baseV + (size_t)r * 4096 + kv + (bc >> 1), &sV[buf][e * 8]);
    }
  };

  stage(0, 0);

  for (int t = 0; t < nt; ++t) {
    __syncthreads();                 // drains stage loads + prev-buf readers
    if (t + 1 < nt) stage((t + 1) & 1, t + 1);
    const u16* bK = sK[t & 1];
    const u16* bV = sV[t & 1];
    const int kv0 = t * 64;

    // QK^T: K-frag read once, used by both q-frags
    f32x4 s2[2][4] = {};
#pragma unroll
    for (int n = 0; n < 4; ++n) {
      int row = n * 16 + lo;
#pragma unroll
      for (int c = 0; c < 4; ++c) {
        int boff = ((c * 32 + hi * 8) * 2) ^ ((row & 7) << 4);
        bf16x8 kf = *(const bf16x8*)((const char*)bK + row * 256 + boff);
        s2[0][n] = MFMA16(qf[0][c], kf, s2[0][n]);
        s2[1][n] = MFMA16(qf[1][c], kf, s2[1][n]);
      }
    }

    bf16x8 pf[2][2];
    u16* myP = sP[wid];
#pragma unroll
    for (int f = 0; f < 2; ++f) {
      const int qrow = q0 + wid * 32 + f * 16;
      const bool diag = (kv0 + 63 > qrow);
      float mt[4] = {-3e38f, -3e38f, -3e38f, -3e38f};
#pragma unroll
      for (int n = 0; n < 4; ++n)
#pragma unroll
        for (int r = 0; r < 4; ++r) {
          float xv = s2[f][n][r] * SM_SCALE;
          if (diag && (kv0 + n * 16 + lo > qrow + hi * 4 + r)) xv = -3e38f;
          s2[f][n][r] = xv;
          mt[r] = fmaxf(mt[r], xv);
        }
#pragma unroll
      for (int d = 1; d < 16; d <<= 1)
#pragma unroll
        for (int r = 0; r < 4; ++r) mt[r] = fmaxf(mt[r], __shfl_xor(mt[r], d));

      float fr[4], rs[4];
#pragma unroll
      for (int r = 0; r < 4; ++r) {
        float mn = fmaxf(m[f][r], mt[r]);
        fr[r] = __expf(m[f][r] - mn);
        m[f][r] = mn;
        rs[r] = 0.f;
      }
#pragma unroll
      for (int n = 0; n < 4; ++n)
#pragma unroll
        for (int r = 0; r < 4; ++r) {
          float p = __expf(s2[f][n][r] - m[f][r]);
          s2[f][n][r] = p;
          rs[r] += p;
        }
#pragma unroll
      for (int d = 1; d < 16; d <<= 1)
#pragma unroll
        for (int r = 0; r < 4; ++r) rs[r] += __shfl_xor(rs[r], d);
#pragma unroll
      for (int r = 0; r < 4; ++r) ls[f][r] = ls[f][r] * fr[r] + rs[r];
#pragma unroll
      for (int d8 = 0; d8 < 8; ++d8)
#pragma unroll
        for (int r = 0; r < 4; ++r) o2[f][d8][r] *= fr[r];

      // P: C-layout (row=hi*4+r, col=n*16+lo) -> LDS -> A-frag layout
#pragma unroll
      for (int n = 0; n < 4; ++n)
#pragma unroll
        for (int r = 0; r < 4; ++r)
          myP[(hi * 4 + r) * 72 + n * 16 + lo] = f32_to_bf16(s2[f][n][r]);
#pragma unroll
      for (int kc = 0; kc < 2; ++kc)
        pf[f][kc] = *(const bf16x8*)(myP + lo * 72 + kc * 32 + hi * 8);
    }

    // PV: V-frag read once, used by both q-frags
#pragma unroll
    for (int kc = 0; kc < 2; ++kc)
#pragma unroll
      for (int d8 = 0; d8 < 8; ++d8) {
        int row = d8 * 16 + lo;
        int boff = ((kc * 32 + hi * 8) * 2) ^ ((row & 7) << 4);
        bf16x8 vf = *(const bf16x8*)((const char*)bV + row * 128 + boff);
        o2[0][d8] = MFMA16(pf[0][kc], vf, o2[0][d8]);
        o2[1][d8] = MFMA16(pf[1][kc], vf, o2[1][d8]);
      }
  }

  // normalize + store (O: [tok][feat] bf16)
#pragma unroll
  for (int f = 0; f < 2; ++f)
#pragma unroll
    for (int r = 0; r < 4; ++r) {
      float inv = 1.f / ls[f][r];
      size_t row = (size_t)b * 2048 + q0 + wid * 32 + f * 16 + hi * 4 + r;
#pragma unroll
      for (int d8 = 0; d8 < 8; ++d8)
        O[row * 2048 + (size_t)h * 128 + d8 * 16 + lo] =
            f32_to_bf16(o2[f][d8][r] * inv);
    }
}

// ---------- launch ----------
extern "C" void kernel_launch(void* const* d_in, const int* in_sizes, int n_in,
                              void* d_out, int out_size, void* d_ws, size_t ws_size,
                              hipStream_t stream) {
  const float* x  = (const float*)d_in[0];
  const float* Wq = (const float*)d_in[1];
  const float* Wk = (const float*)d_in[2];
  const float* Wv = (const float*)d_in[3];
  const float* Wo = (const float*)d_in[4];
  float* out = (float*)d_out;

  constexpr int B = 2, S = 2048, D = 2048;
  constexpr int M = B * S;  // 4096

  char* ws = (char*)d_ws;
  u16* xb  = (u16*)ws; ws += (size_t)M * D * 2;
  u16* wqb = (u16*)ws; ws += (size_t)D * D * 2;
  u16* wkb = (u16*)ws; ws += (size_t)D * D * 2;
  u16* wvb = (u16*)ws; ws += (size_t)D * D * 2;
  u16* wob = (u16*)ws; ws += (size_t)D * D * 2;
  u16* q   = (u16*)ws; ws += (size_t)M * D * 2;
  u16* k   = (u16*)ws; ws += (size_t)M * D * 2;
  u16* vT  = (u16*)ws; ws += (size_t)M * D * 2;   // [feat 2048][tok 4096]
  u16* att = (u16*)ws; ws += (size_t)M * D * 2;

  cast_kernel<<<M * D / 1024, 256, 0, stream>>>(x, xb, M * D);
  cast_kernel<<<D * D / 1024, 256, 0, stream>>>(Wq, wqb, D * D);
  cast_kernel<<<D * D / 1024, 256, 0, stream>>>(Wk, wkb, D * D);
  cast_kernel<<<D * D / 1024, 256, 0, stream>>>(Wv, wvb, D * D);
  cast_kernel<<<D * D / 1024, 256, 0, stream>>>(Wo, wob, D * D);

  dim3 gg(D / 128, M / 128);
  gemm_nt<u16><<<gg, 256, 0, stream>>>(xb, wqb, q, M, D, D);
  gemm_nt<u16><<<gg, 256, 0, stream>>>(xb, wkb, k, M, D, D);
  // V^T = Wv * x^T : output [feature][token] — free transpose for attention
  gemm_nt<u16><<<dim3(M / 128, D / 128), 256, 0, stream>>>(wvb, xb, vT, D, M, D);

  attn_fwd<<<dim3(16, 16, B), 256, 0, stream>>>(q, k, vT, att);

  gemm_nt<float><<<gg, 256, 0, stream>>>(att, wob, out, M, D, D);
}

// Round 4
// 278.272 us; speedup vs baseline: 1.5577x; 1.0987x over previous
//
#include <hip/hip_runtime.h>
#include <hip/hip_bf16.h>
#include <type_traits>

#define DEV __device__ __forceinline__

typedef __bf16 bf16x8 __attribute__((ext_vector_type(8)));
typedef float f32x4 __attribute__((ext_vector_type(4)));
typedef float f32x16 __attribute__((ext_vector_type(16)));
typedef unsigned short u16;
typedef unsigned int u32;

// ---------- helpers ----------
DEV u16 f32_to_bf16(float f) {                 // round-to-nearest-even
  union { float f; u32 u; } x; x.f = f;
  u32 r = (x.u + 0x7FFFu + ((x.u >> 16) & 1u)) >> 16;
  return (u16)r;
}

DEV u32 pack_bf16(float a, float b) {
  return (u32)f32_to_bf16(a) | ((u32)f32_to_bf16(b) << 16);
}

// async global->LDS, 16B per lane. HW writes wave-uniform base + lane*16 (linear).
DEV void ld_lds16(const void* g, void* l) {
  __builtin_amdgcn_global_load_lds(
      (const __attribute__((address_space(1))) u32*)g,
      (__attribute__((address_space(3))) u32*)l, 16, 0, 0);
}

#define MFMA16(a, b, c) __builtin_amdgcn_mfma_f32_16x16x32_bf16(a, b, c, 0, 0, 0)
#define MFMA32(a, b, c) __builtin_amdgcn_mfma_f32_32x32x16_bf16(a, b, c, 0, 0, 0)

// ---------- cast f32 -> bf16 (vectorized, memory-bound) ----------
__global__ __launch_bounds__(256) void cast_kernel(const float* __restrict__ in,
                                                   u16* __restrict__ out, int n) {
  int i = (blockIdx.x * 256 + threadIdx.x) * 4;
  if (i >= n) return;
  float4 v = *reinterpret_cast<const float4*>(in + i);
  ushort4 o;
  o.x = f32_to_bf16(v.x); o.y = f32_to_bf16(v.y);
  o.z = f32_to_bf16(v.z); o.w = f32_to_bf16(v.w);
  *reinterpret_cast<ushort4*>(out + i) = o;
}

// ---------- GEMM: C[M][N] = A[M][K] * B[N][K]^T  (bf16 in, f32 acc) ----------
template <typename OutT>
__global__ __launch_bounds__(256) void gemm_nt(const u16* __restrict__ A,
                                               const u16* __restrict__ B,
                                               OutT* __restrict__ C,
                                               int M, int N, int K) {
  __shared__ __align__(16) u16 sA[128 * 64];
  __shared__ __align__(16) u16 sB[128 * 64];
  const int tid = threadIdx.x;
  const int lane = tid & 63, wid = tid >> 6;
  const int lo = lane & 15, hi = lane >> 4;
  const int wm = wid >> 1, wn = wid & 1;
  const int m0 = blockIdx.y * 128, n0 = blockIdx.x * 128;

  f32x4 acc[4][4] = {};

  for (int k0 = 0; k0 < K; k0 += 64) {
    __syncthreads();
#pragma unroll
    for (int i = 0; i < 4; ++i) {
      int e16 = i * 256 + tid;
      int r = e16 >> 3;
      int bcol = ((e16 & 7) * 16) ^ ((r & 7) << 4);
      int col = bcol >> 1;
      ld_lds16(A + (size_t)(m0 + r) * K + k0 + col, sA + e16 * 8);
      ld_lds16(B + (size_t)(n0 + r) * K + k0 + col, sB + e16 * 8);
    }
    __syncthreads();
#pragma unroll
    for (int kc = 0; kc < 2; ++kc) {
      bf16x8 a[4], b[4];
#pragma unroll
      for (int i = 0; i < 4; ++i) {
        int row = wm * 64 + i * 16 + lo;
        int boff = ((kc * 32 + hi * 8) * 2) ^ ((row & 7) << 4);
        a[i] = *(const bf16x8*)((const char*)sA + row * 128 + boff);
      }
#pragma unroll
      for (int i = 0; i < 4; ++i) {
        int row = wn * 64 + i * 16 + lo;
        int boff = ((kc * 32 + hi * 8) * 2) ^ ((row & 7) << 4);
        b[i] = *(const bf16x8*)((const char*)sB + row * 128 + boff);
      }
#pragma unroll
      for (int mi = 0; mi < 4; ++mi)
#pragma unroll
        for (int ni = 0; ni < 4; ++ni)
          acc[mi][ni] = MFMA16(a[mi], b[ni], acc[mi][ni]);
    }
  }
#pragma unroll
  for (int mi = 0; mi < 4; ++mi)
#pragma unroll
    for (int r = 0; r < 4; ++r) {
      size_t row = m0 + wm * 64 + mi * 16 + hi * 4 + r;
#pragma unroll
      for (int ni = 0; ni < 4; ++ni) {
        int col = n0 + wn * 64 + ni * 16 + lo;
        float v = acc[mi][ni][r];
        if constexpr (std::is_same<OutT, float>::value)
          C[row * N + col] = v;
        else
          C[row * N + col] = f32_to_bf16(v);
      }
    }
}

// ---------- causal flash attention (swapped-operand 32x32, in-reg softmax) ----
// Q,K: [tok 4096][feat 2048]; VT: [feat 2048][tok 4096].
// 4 waves x 32 q-rows = 128 q/block; KV tile 64 (2 key-blocks of 32).
// S = mfma(K, Q): lane holds 32 P-values (keys) for query lane&31 ->
// softmax in-register; cross-half combine + P redistribution via shfl_xor(32)
// (known-good semantics; permlane direction was the round-3 failure suspect).
constexpr float SM_SCALE = 0.08838834764831845f;  // 1/sqrt(128)
constexpr float RTHR = 8.0f / SM_SCALE;           // defer-max threshold (raw)

__global__ __launch_bounds__(256, 2) void attn_fwd(const u16* __restrict__ Q,
                                                   const u16* __restrict__ K,
                                                   const u16* __restrict__ VT,
                                                   u16* __restrict__ O) {
  __shared__ __align__(16) u16 sK[2][64 * 128];   // [kv 64][dh 128], swizzled
  __shared__ __align__(16) u16 sV[2][128 * 64];   // [dh 128][kv 64], swizzled

  const int x = blockIdx.x, h = blockIdx.y, b = blockIdx.z;
  const int qt = b ? x : (15 - x);   // anti-correlated pairing across batch
  const int tid = threadIdx.x;
  const int lane = tid & 63, wid = tid >> 6;
  const int l31 = lane & 31, hi5 = lane >> 5;

  const size_t baseQK = ((size_t)b * 2048) * 2048 + (size_t)h * 128;
  const size_t baseV  = ((size_t)h * 128) * 4096 + (size_t)b * 2048;
  const int q0 = qt * 128;
  const int qw = q0 + wid * 32;      // wave's first query row
  const int qg = qw + l31;           // this lane's query row
  const int nt = 2 * qt + 2;

  // Q B-fragments in registers: Q[qg][kc*16 + hi5*8 + 0..7]
  bf16x8 qf[8];
#pragma unroll
  for (int kc = 0; kc < 8; ++kc)
    qf[kc] = *(const bf16x8*)(Q + baseQK + (size_t)qg * 2048 + kc * 16 + hi5 * 8);

  f32x16 o[4] = {};                  // O^T: [dh block d*32 + rowpat][q=l31]
  float m = -INFINITY, ls = 0.f;

  auto stage = [&](int buf, int t) {
    const int kv = t * 64;
#pragma unroll
    for (int i = 0; i < 4; ++i) {    // K tile: 64 rows x 256B
      int e = i * 256 + tid;
      int r = e >> 4;
      int bc = ((e & 15) * 16) ^ ((r & 7) << 4);
      ld_lds16(K + baseQK + (size_t)(kv + r) * 2048 + (bc >> 1), &sK[buf][e * 8]);
    }
#pragma unroll
    for (int i = 0; i < 4; ++i) {    // VT tile: 128 rows x 128B
      int e = i * 256 + tid;
      int r = e >> 3;
      int bc = ((e & 7) * 16) ^ ((r & 7) << 4);
      ld_lds16(VT + baseV + (size_t)r * 4096 + kv + (bc >> 1), &sV[buf][e * 8]);
    }
  };

  stage(0, 0);

  for (int t = 0; t < nt; ++t) {
    __syncthreads();                 // stage(t) complete; prev readers done
    if (t + 1 < nt) stage((t + 1) & 1, t + 1);
    const int kv0 = t * 64;
    if (kv0 > qw + 31) continue;     // tile fully masked for this wave
    const u16* bK = sK[t & 1];
    const u16* bV = sV[t & 1];

    // ---- S = K * Q^T : lane holds S[key(j,hi5)+kb*32][q=l31] ----
    f32x16 s[2] = {};
#pragma unroll
    for (int kb = 0; kb < 2; ++kb) {
      int row = kb * 32 + l31;
      int rsw = (row & 7) << 4;
#pragma unroll
      for (int kc = 0; kc < 8; ++kc) {
        int bo = (kc * 32 + hi5 * 16) ^ rsw;
        bf16x8 kf = *(const bf16x8*)((const char*)bK + row * 256 + bo);
        s[kb] = MFMA32(kf, qf[kc], s[kb]);
      }
    }

    // ---- mask (diag tiles only) ----
    if (kv0 + 63 > qw) {
#pragma unroll
      for (int kb = 0; kb < 2; ++kb)
#pragma unroll
        for (int j = 0; j < 16; ++j) {
          int keyg = kv0 + kb * 32 + (j & 3) + 8 * (j >> 2) + 4 * hi5;
          s[kb][j] = (keyg > qg) ? -3e38f : s[kb][j];
        }
    }

    // ---- row max: in-lane + cross-half shfl ----
    float pmax = -3e38f;
#pragma unroll
    for (int kb = 0; kb < 2; ++kb)
#pragma unroll
      for (int j = 0; j < 16; ++j) pmax = fmaxf(pmax, s[kb][j]);
    pmax = fmaxf(pmax, __shfl_xor(pmax, 32));

    // ---- defer-max rescale ----
    if (!__all(pmax - m <= RTHR)) {
      float mn = fmaxf(m, pmax);
      float fr = __expf((m - mn) * SM_SCALE);
      ls *= fr;
#pragma unroll
      for (int d = 0; d < 4; ++d) o[d] *= fr;
      m = mn;
    }

    // ---- exp + row sum ----
    float rs = 0.f;
#pragma unroll
    for (int kb = 0; kb < 2; ++kb)
#pragma unroll
      for (int j = 0; j < 16; ++j) {
        float p = __expf((s[kb][j] - m) * SM_SCALE);
        s[kb][j] = p;
        rs += p;
      }
    rs += __shfl_xor(rs, 32);
    ls += rs;

    // ---- pack P to bf16 pairs, redistribute into PV B-frags ----
    // lane (half hi5') holds keys 16gp + 4*hi5' + {2w,2w+1} (aa group) and
    // 16gp + 8 + 4*hi5' + {2w,2w+1} (bb group) in s[kb].
    // B-frag pf[2kb+gp] lane (half h) word w' needs keys 16gp+8h+2w',2w'+1:
    //   h=0: [own aa0, own aa1, partner aa0, partner aa1]
    //   h=1: [partner bb0, partner bb1, own bb0, own bb1]
    union PF { u32 w[4]; bf16x8 v; };
    PF pf[4];
#pragma unroll
    for (int kb = 0; kb < 2; ++kb)
#pragma unroll
      for (int gp = 0; gp < 2; ++gp) {
        u32 keep[2], send[2];
#pragma unroll
        for (int w = 0; w < 2; ++w) {
          int ja = 8 * gp + 2 * w;          // aa pair (keys 16gp+4hi5+2w,+1)
          int jb = 8 * gp + 4 + 2 * w;      // bb pair (keys 16gp+8+4hi5+2w,+1)
          u32 aa = pack_bf16(s[kb][ja], s[kb][ja + 1]);
          u32 bb = pack_bf16(s[kb][jb], s[kb][jb + 1]);
          keep[w] = hi5 ? bb : aa;
          send[w] = hi5 ? aa : bb;
        }
        u32 recv0 = (u32)__shfl_xor((int)send[0], 32);
        u32 recv1 = (u32)__shfl_xor((int)send[1], 32);
        PF& f = pf[2 * kb + gp];
        f.w[0] = hi5 ? recv0 : keep[0];
        f.w[1] = hi5 ? recv1 : keep[1];
        f.w[2] = hi5 ? keep[0] : recv0;
        f.w[3] = hi5 ? keep[1] : recv1;
      }

    // ---- O^T += V^T * P ----
#pragma unroll
    for (int d = 0; d < 4; ++d) {
      int row = d * 32 + l31;
      int rsw = (row & 7) << 4;
#pragma unroll
      for (int ks = 0; ks < 4; ++ks) {
        int bo = (ks * 32 + hi5 * 16) ^ rsw;
        bf16x8 vf = *(const bf16x8*)((const char*)bV + row * 128 + bo);
        o[d] = MFMA32(vf, pf[ks].v, o[d]);
      }
    }
  }

  // ---- normalize + store: O[tok][feat], 8B stores ----
  float inv = 1.f / ls;
  size_t orow = (size_t)b * 2048 + qg;
#pragma unroll
  for (int d = 0; d < 4; ++d)
#pragma unroll
    for (int G = 0; G < 4; ++G) {
      ushort4 st;
      st.x = f32_to_bf16(o[d][4 * G + 0] * inv);
      st.y = f32_to_bf16(o[d][4 * G + 1] * inv);
      st.z = f32_to_bf16(o[d][4 * G + 2] * inv);
      st.w = f32_to_bf16(o[d][4 * G + 3] * inv);
      int col = h * 128 + d * 32 + 8 * G + 4 * hi5;
      *(ushort4*)(O + orow * 2048 + col) = st;
    }
}

// ---------- launch ----------
extern "C" void kernel_launch(void* const* d_in, const int* in_sizes, int n_in,
                              void* d_out, int out_size, void* d_ws, size_t ws_size,
                              hipStream_t stream) {
  const float* x  = (const float*)d_in[0];
  const float* Wq = (const float*)d_in[1];
  const float* Wk = (const float*)d_in[2];
  const float* Wv = (const float*)d_in[3];
  const float* Wo = (const float*)d_in[4];
  float* out = (float*)d_out;

  constexpr int B = 2, S = 2048, D = 2048;
  constexpr int M = B * S;  // 4096

  char* ws = (char*)d_ws;
  u16* xb  = (u16*)ws; ws += (size_t)M * D * 2;
  u16* wqb = (u16*)ws; ws += (size_t)D * D * 2;
  u16* wkb = (u16*)ws; ws += (size_t)D * D * 2;
  u16* wvb = (u16*)ws; ws += (size_t)D * D * 2;
  u16* wob = (u16*)ws; ws += (size_t)D * D * 2;
  u16* q   = (u16*)ws; ws += (size_t)M * D * 2;
  u16* k   = (u16*)ws; ws += (size_t)M * D * 2;
  u16* vT  = (u16*)ws; ws += (size_t)M * D * 2;   // [feat 2048][tok 4096]
  u16* att = (u16*)ws; ws += (size_t)M * D * 2;

  cast_kernel<<<M * D / 1024, 256, 0, stream>>>(x, xb, M * D);
  cast_kernel<<<D * D / 1024, 256, 0, stream>>>(Wq, wqb, D * D);
  cast_kernel<<<D * D / 1024, 256, 0, stream>>>(Wk, wkb, D * D);
  cast_kernel<<<D * D / 1024, 256, 0, stream>>>(Wv, wvb, D * D);
  cast_kernel<<<D * D / 1024, 256, 0, stream>>>(Wo, wob, D * D);

  dim3 gg(D / 128, M / 128);
  gemm_nt<u16><<<gg, 256, 0, stream>>>(xb, wqb, q, M, D, D);
  gemm_nt<u16><<<gg, 256, 0, stream>>>(xb, wkb, k, M, D, D);
  // V^T = Wv * x^T : output [feature][token] — free transpose for attention
  gemm_nt<u16><<<dim3(M / 128, D / 128), 256, 0, stream>>>(wvb, xb, vT, D, M, D);

  attn_fwd<<<dim3(16, 16, B), 256, 0, stream>>>(q, k, vT, att);

  gemm_nt<float><<<gg, 256, 0, stream>>>(att, wob, out, M, D, D);
}